// Round 1
// baseline (497.161 us; speedup 1.0000x reference)
//
#include <hip/hip_runtime.h>
#include <math.h>

#define DIM      4096
#define NE       64
#define M_TOK    16384   // B*S = 4*4096
#define BM       64      // tokens per block tile
#define BK       32      // k-slice per stage
#define LDS_LD   66      // padded leading dim (2-way conflicts max = free)

// ---------------------------------------------------------------------------
// Kernel 1: tiled fp32 GEMM  logits[t][e] = sum_k x[t][k]*W[e][k]
// Grid: (M_TOK/BM, KS). Each block does K range [ks*kQ, (ks+1)*kQ).
// Partial for ks==0 goes to part0 (the routing_probs region of d_out),
// ks>=1 to ws. float2 stores (part0 base is only 8B-aligned).
// ---------------------------------------------------------------------------
__global__ __launch_bounds__(256) void gemm_logits(
    const float* __restrict__ x, const float* __restrict__ W,
    float* __restrict__ part0, float* __restrict__ wsp, int kQ)
{
    const int mt  = blockIdx.x;
    const int ks  = blockIdx.y;
    const int tid = threadIdx.x;
    const int tx  = tid & 15;   // expert group (4 experts)
    const int ty  = tid >> 4;   // token group (4 tokens)
    const int tok0 = mt * BM;
    const int k0   = ks * kQ;

    __shared__ float Xs[BK][LDS_LD];
    __shared__ float Ws[BK][LDS_LD];

    float acc[4][4] = {};

    for (int kt = k0; kt < k0 + kQ; kt += BK) {
        // ---- stage X tile (64 tok x 32 k) and W tile (64 exp x 32 k), transposed
        #pragma unroll
        for (int j = 0; j < 2; ++j) {
            const int f   = tid + 256 * j;   // float4 index 0..511
            const int row = f >> 3;          // 0..63
            const int c4  = f & 7;           // 0..7
            const float4 xv = *reinterpret_cast<const float4*>(
                &x[(size_t)(tok0 + row) * DIM + kt + c4 * 4]);
            Xs[c4 * 4 + 0][row] = xv.x;
            Xs[c4 * 4 + 1][row] = xv.y;
            Xs[c4 * 4 + 2][row] = xv.z;
            Xs[c4 * 4 + 3][row] = xv.w;
            const float4 wv = *reinterpret_cast<const float4*>(
                &W[(size_t)row * DIM + kt + c4 * 4]);
            Ws[c4 * 4 + 0][row] = wv.x;
            Ws[c4 * 4 + 1][row] = wv.y;
            Ws[c4 * 4 + 2][row] = wv.z;
            Ws[c4 * 4 + 3][row] = wv.w;
        }
        __syncthreads();

        #pragma unroll
        for (int kk = 0; kk < BK; ++kk) {
            float a[4], b[4];
            #pragma unroll
            for (int i = 0; i < 4; ++i) a[i] = Xs[kk][ty * 4 + i];
            #pragma unroll
            for (int j = 0; j < 4; ++j) b[j] = Ws[kk][tx * 4 + j];
            #pragma unroll
            for (int i = 0; i < 4; ++i)
                #pragma unroll
                for (int j = 0; j < 4; ++j)
                    acc[i][j] = fmaf(a[i], b[j], acc[i][j]);
        }
        __syncthreads();
    }

    float* outp = (ks == 0) ? part0 : (wsp + (size_t)(ks - 1) * (M_TOK * NE));
    #pragma unroll
    for (int i = 0; i < 4; ++i) {
        const size_t off = (size_t)(tok0 + ty * 4 + i) * NE + tx * 4;
        *reinterpret_cast<float2*>(&outp[off])     = make_float2(acc[i][0], acc[i][1]);
        *reinterpret_cast<float2*>(&outp[off + 2]) = make_float2(acc[i][2], acc[i][3]);
    }
}

// ---------------------------------------------------------------------------
// Kernel 2: per-token epilogue. One wave per token, lane = expert.
// probs_logits holds ks=0 partial logits on entry; probs on exit.
// ---------------------------------------------------------------------------
__global__ __launch_bounds__(256) void epilogue(
    float* probs_logits, const float* __restrict__ wsp, int KS,
    float* __restrict__ out_w, float* __restrict__ out_idx,
    float* __restrict__ out_usage, float* __restrict__ z_acc)
{
    const int tid  = threadIdx.x;
    const int lane = tid & 63;
    const int w    = tid >> 6;
    const int tok0 = blockIdx.x * 64;

    float local_usage = 0.f;
    float local_z     = 0.f;

    for (int i = 0; i < 16; ++i) {
        const int t = tok0 + w * 16 + i;
        const size_t base = (size_t)t * NE + lane;
        float v = probs_logits[base];
        for (int s = 1; s < KS; ++s)
            v += wsp[(size_t)(s - 1) * (M_TOK * NE) + base];

        // argmax (tie-break: lower index, matching jax.lax.top_k)
        float m = v; int mi = lane;
        #pragma unroll
        for (int off = 32; off >= 1; off >>= 1) {
            const float om = __shfl_xor(m, off);
            const int   oi = __shfl_xor(mi, off);
            if (om > m || (om == m && oi < mi)) { m = om; mi = oi; }
        }
        const float m1 = m; const int i1 = mi;

        // second max, excluding argmax lane
        float m2 = (lane == i1) ? -INFINITY : v; int mi2 = lane;
        #pragma unroll
        for (int off = 32; off >= 1; off >>= 1) {
            const float om = __shfl_xor(m2, off);
            const int   oi = __shfl_xor(mi2, off);
            if (om > m2 || (om == m2 && oi < mi2)) { m2 = om; mi2 = oi; }
        }

        // softmax over all 64 experts
        const float e = expf(v - m1);
        float s = e;
        #pragma unroll
        for (int off = 32; off >= 1; off >>= 1) s += __shfl_xor(s, off);
        const float p = e / s;
        probs_logits[base] = p;
        local_usage += p;

        const float lse = m1 + logf(s);
        local_z += lse * lse;

        if (lane == 0) {
            const float d   = expf(m2 - m1);
            const float inv = 1.f / (1.f + d);
            out_w[t * 2]     = inv;          // softmax([m1, m2])
            out_w[t * 2 + 1] = d * inv;
            out_idx[t * 2]     = (float)i1;  // indices as float values
            out_idx[t * 2 + 1] = (float)mi2;
        }
    }

    // block-level reductions
    __shared__ float us[4][NE];
    __shared__ float zs[4];
    us[w][lane] = local_usage;
    if (lane == 0) zs[w] = local_z;
    __syncthreads();
    if (tid < NE) {
        const float su = us[0][tid] + us[1][tid] + us[2][tid] + us[3][tid];
        atomicAdd(&out_usage[tid], su);
    }
    if (tid == 0) atomicAdd(z_acc, zs[0] + zs[1] + zs[2] + zs[3]);
}

// ---------------------------------------------------------------------------
// Kernel 3: finalize usage mean, load-balance loss, z-loss mean.
// ---------------------------------------------------------------------------
__global__ void finalize(float* usage, float* lb, float* z)
{
    const int e = threadIdx.x;   // 64 threads
    const float u = usage[e] * (1.f / (float)M_TOK);
    usage[e] = u;
    float s = u * u;
    #pragma unroll
    for (int off = 32; off >= 1; off >>= 1) s += __shfl_xor(s, off);
    if (e == 0) {
        lb[0] = s * (float)NE;
        z[0]  = z[0] * (1.f / (float)M_TOK);
    }
}

// ---------------------------------------------------------------------------
extern "C" void kernel_launch(void* const* d_in, const int* in_sizes, int n_in,
                              void* d_out, int out_size, void* d_ws, size_t ws_size,
                              hipStream_t stream)
{
    const float* x = (const float*)d_in[0];
    const float* W = (const float*)d_in[1];
    float* o = (float*)d_out;

    // output layout (flat fp32, reference return order):
    float* out_w     = o;            // [16384][2]
    float* out_idx   = o + 32768;    // [16384][2] (as floats)
    float* out_lb    = o + 65536;    // scalar
    float* out_z     = o + 65537;    // scalar
    float* out_usage = o + 65538;    // [64]
    float* out_probs = o + 65602;    // [16384][64]

    const size_t partBytes = (size_t)M_TOK * NE * sizeof(float); // 4 MB
    int KS = 1;
    if      (ws_size >= 7 * partBytes) KS = 8;
    else if (ws_size >= 3 * partBytes) KS = 4;
    else if (ws_size >= 1 * partBytes) KS = 2;

    // zero accumulators: z (1) + usage (64)
    hipMemsetAsync(out_z, 0, 65 * sizeof(float), stream);

    dim3 g1(M_TOK / BM, KS);
    gemm_logits<<<g1, 256, 0, stream>>>(x, W, out_probs, (float*)d_ws, DIM / KS);
    epilogue<<<M_TOK / 64, 256, 0, stream>>>(out_probs, (const float*)d_ws, KS,
                                             out_w, out_idx, out_usage, out_z);
    finalize<<<1, 64, 0, stream>>>(out_usage, out_lb, out_z);
}